// Round 3
// baseline (46.527 us; speedup 1.0000x reference)
//
#include <hip/hip_runtime.h>
#include <math.h>

#define NN 2048
#define INDIM 256
#define ODIM 64
#define NH 8
#define DHD 8
#define LOG2E 1.44269504088896340736f

// K1: wh = h@W^T + b ; eiL = (ei+ab)*log2e ; ejL = ej*log2e
// 256 blocks x 256 threads; 8 nodes/block, 2 nodes per wave (lane = out col).
__global__ __launch_bounds__(256) void gat_pre(
    const float* __restrict__ h, const float* __restrict__ Ww,
    const float* __restrict__ Wb, const float* __restrict__ aw,
    const float* __restrict__ ab,
    float* __restrict__ wh, float* __restrict__ eiL, float* __restrict__ ejL)
{
    __shared__ float sH[8][INDIM];           // 8 KB
    const int t = threadIdx.x;
    const int n0 = blockIdx.x * 8;
    {
        const float4* src = (const float4*)(h + (size_t)n0 * INDIM);
        float4* dst = (float4*)&sH[0][0];
        dst[t] = src[t];
        dst[t + 256] = src[t + 256];
    }
    __syncthreads();

    const int o  = t & 63;
    const int wv = t >> 6;
    const int nb = wv * 2;                   // 2 nodes per wave
    const float4* w4 = (const float4*)(Ww + (size_t)o * INDIM);
    float a0 = 0.f, a1 = 0.f;
#pragma unroll 8
    for (int k = 0; k < INDIM / 4; ++k) {
        const float4 wk = w4[k];
        const float4 h0 = *(const float4*)&sH[nb + 0][k * 4];
        const float4 h1 = *(const float4*)&sH[nb + 1][k * 4];
        a0 = fmaf(wk.x, h0.x, a0); a0 = fmaf(wk.y, h0.y, a0);
        a0 = fmaf(wk.z, h0.z, a0); a0 = fmaf(wk.w, h0.w, a0);
        a1 = fmaf(wk.x, h1.x, a1); a1 = fmaf(wk.y, h1.y, a1);
        a1 = fmaf(wk.z, h1.z, a1); a1 = fmaf(wk.w, h1.w, a1);
    }
    const float bias = Wb[o];
    float accs[2] = {a0 + bias, a1 + bias};

    const int d = o & 7;
    const float aL = aw[d], aR = aw[NH + d];
    const float abv = ab[0];
#pragma unroll
    for (int r = 0; r < 2; ++r) {
        const int n = n0 + nb + r;
        wh[(size_t)n * ODIM + o] = accs[r];
        float pi = accs[r] * aL;
        float pj = accs[r] * aR;
        pi += __shfl_xor(pi, 1, 64); pj += __shfl_xor(pj, 1, 64);
        pi += __shfl_xor(pi, 2, 64); pj += __shfl_xor(pj, 2, 64);
        pi += __shfl_xor(pi, 4, 64); pj += __shfl_xor(pj, 4, 64);
        if (d == 0) {
            const int hd = o >> 3;
            eiL[n * NH + hd] = (pi + abv) * LOG2E;
            ejL[n * NH + hd] = pj * LOG2E;
        }
    }
}

// K2: 8 i-rows per block, 1024 threads = 128 j-lanes x 8 heads (16 waves,
// 4 waves/SIMD). Adjacency bit-packed in LDS: s_bits[j] bit i = adj[i0+i][j].
__global__ __launch_bounds__(1024, 4) void gat_main(
    const int* __restrict__ adj, const float* __restrict__ wh,
    const float* __restrict__ eiL, const float* __restrict__ ejL,
    float* __restrict__ out)
{
    __shared__ unsigned char s_bits[NN];     // 2 KB
    __shared__ float s_red[16][8][8][9];     // 36 KB: wave, head, i, d/den
    const int t  = threadIdx.x;
    const int i0 = blockIdx.x * 8;

    {   // stage + bit-pack: thread t owns columns 2t, 2t+1
        unsigned int b0 = 0, b1 = 0;
#pragma unroll
        for (int i = 0; i < 8; ++i) {
            const int2 v = *(const int2*)(adj + (size_t)(i0 + i) * NN + 2 * t);
            b0 |= (v.x != 0) << i;
            b1 |= (v.y != 0) << i;
        }
        s_bits[2 * t]     = (unsigned char)b0;
        s_bits[2 * t + 1] = (unsigned char)b1;
    }
    __syncthreads();

    const int hh = t & 7;
    const int jj = t >> 3;                   // 0..127
    float eih[8];
#pragma unroll
    for (int i = 0; i < 8; ++i) eih[i] = eiL[(i0 + i) * NH + hh];

    float den[8];
    float acc[8][8];
#pragma unroll
    for (int i = 0; i < 8; ++i) {
        den[i] = 0.f;
#pragma unroll
        for (int d2 = 0; d2 < 8; ++d2) acc[i][d2] = 0.f;
    }

    for (int it = 0; it < NN / 128; ++it) {
        const int j = (it << 7) | jj;
        const int bits = s_bits[j];
        const float ejv = ejL[j * NH + hh];
        const float4* wr = (const float4*)(wh + (size_t)j * ODIM + hh * DHD);
        const float4 w0 = wr[0];
        const float4 w1 = wr[1];
#pragma unroll
        for (int i = 0; i < 8; ++i) {
            float s = eih[i] + ejv;          // score * log2e
            s = fmaxf(s, 0.2f * s);          // LeakyReLU (commutes with +scale)
            const float e = exp2f(s);
            const float w = (bits & (1 << i)) ? e : 0.0f;
            den[i] += w;
            acc[i][0] = fmaf(w, w0.x, acc[i][0]);
            acc[i][1] = fmaf(w, w0.y, acc[i][1]);
            acc[i][2] = fmaf(w, w0.z, acc[i][2]);
            acc[i][3] = fmaf(w, w0.w, acc[i][3]);
            acc[i][4] = fmaf(w, w1.x, acc[i][4]);
            acc[i][5] = fmaf(w, w1.y, acc[i][5]);
            acc[i][6] = fmaf(w, w1.z, acc[i][6]);
            acc[i][7] = fmaf(w, w1.w, acc[i][7]);
        }
    }

    // reduce over the 8 j-lane groups within each wave (lane bits 3..5)
#pragma unroll
    for (int m = 8; m <= 32; m <<= 1) {
#pragma unroll
        for (int i = 0; i < 8; ++i) {
            den[i] += __shfl_xor(den[i], m, 64);
#pragma unroll
            for (int d2 = 0; d2 < 8; ++d2)
                acc[i][d2] += __shfl_xor(acc[i][d2], m, 64);
        }
    }
    const int lane = t & 63;
    const int wv   = t >> 6;                 // 0..15
    if (lane < 8) {                          // lane == head
#pragma unroll
        for (int i = 0; i < 8; ++i) {
#pragma unroll
            for (int d2 = 0; d2 < 8; ++d2) s_red[wv][lane][i][d2] = acc[i][d2];
            s_red[wv][lane][i][8] = den[i];
        }
    }
    __syncthreads();

    if (t < 512) {                           // 8 i x 8 heads x 8 d
        const int i  = t >> 6;
        const int oh = (t >> 3) & 7;
        const int d2 = t & 7;
        float v = 0.f, dn = 0.f;
#pragma unroll
        for (int w2 = 0; w2 < 16; ++w2) {
            v  += s_red[w2][oh][i][d2];
            dn += s_red[w2][oh][i][8];
        }
        float r = v / dn;
        r = (r > 0.f) ? r : expm1f(r);       // ELU(alpha=1)
        out[(size_t)oh * (NN * DHD) + (size_t)(i0 + i) * DHD + d2] = r;
    }
}

extern "C" void kernel_launch(void* const* d_in, const int* in_sizes, int n_in,
                              void* d_out, int out_size, void* d_ws, size_t ws_size,
                              hipStream_t stream) {
    const float* h   = (const float*)d_in[0];
    const int*   adj = (const int*)d_in[1];
    const float* Ww  = (const float*)d_in[2];
    const float* Wb  = (const float*)d_in[3];
    const float* aw  = (const float*)d_in[4];
    const float* ab  = (const float*)d_in[5];
    float* out = (float*)d_out;

    float* wh  = (float*)d_ws;                // 2048*64 f32
    float* eiL = wh + (size_t)NN * ODIM;      // 2048*8
    float* ejL = eiL + (size_t)NN * NH;       // 2048*8

    gat_pre<<<NN / 8, 256, 0, stream>>>(h, Ww, Wb, aw, ab, wh, eiL, ejL);
    gat_main<<<NN / 8, 1024, 0, stream>>>(adj, wh, eiL, ejL, out);
}

// Round 4
// 44.733 us; speedup vs baseline: 1.0401x; 1.0401x over previous
//
#include <hip/hip_runtime.h>
#include <math.h>

#define NN 2048
#define INDIM 256
#define ODIM 64
#define NH 8
#define DHD 8
#define LOG2E 1.44269504088896340736f

// K1: wh = h@W^T + b ; eiL = (ei+ab)*log2e ; ejL = ej*log2e
// 256 blocks x 256 threads; 8 nodes/block, 2 nodes per wave (lane = out col).
__global__ __launch_bounds__(256) void gat_pre(
    const float* __restrict__ h, const float* __restrict__ Ww,
    const float* __restrict__ Wb, const float* __restrict__ aw,
    const float* __restrict__ ab,
    float* __restrict__ wh, float* __restrict__ eiL, float* __restrict__ ejL)
{
    __shared__ float sH[8][INDIM];           // 8 KB
    const int t = threadIdx.x;
    const int n0 = blockIdx.x * 8;
    {
        const float4* src = (const float4*)(h + (size_t)n0 * INDIM);
        float4* dst = (float4*)&sH[0][0];
        dst[t] = src[t];
        dst[t + 256] = src[t + 256];
    }
    __syncthreads();

    const int o  = t & 63;
    const int wv = t >> 6;
    const int nb = wv * 2;                   // 2 nodes per wave
    const float4* w4 = (const float4*)(Ww + (size_t)o * INDIM);
    float a0 = 0.f, a1 = 0.f;
#pragma unroll 8
    for (int k = 0; k < INDIM / 4; ++k) {
        const float4 wk = w4[k];
        const float4 h0 = *(const float4*)&sH[nb + 0][k * 4];
        const float4 h1 = *(const float4*)&sH[nb + 1][k * 4];
        a0 = fmaf(wk.x, h0.x, a0); a0 = fmaf(wk.y, h0.y, a0);
        a0 = fmaf(wk.z, h0.z, a0); a0 = fmaf(wk.w, h0.w, a0);
        a1 = fmaf(wk.x, h1.x, a1); a1 = fmaf(wk.y, h1.y, a1);
        a1 = fmaf(wk.z, h1.z, a1); a1 = fmaf(wk.w, h1.w, a1);
    }
    const float bias = Wb[o];
    float accs[2] = {a0 + bias, a1 + bias};

    const int d = o & 7;
    const float aL = aw[d], aR = aw[NH + d];
    const float abv = ab[0];
#pragma unroll
    for (int r = 0; r < 2; ++r) {
        const int n = n0 + nb + r;
        wh[(size_t)n * ODIM + o] = accs[r];
        float pi = accs[r] * aL;
        float pj = accs[r] * aR;
        pi += __shfl_xor(pi, 1, 64); pj += __shfl_xor(pj, 1, 64);
        pi += __shfl_xor(pi, 2, 64); pj += __shfl_xor(pj, 2, 64);
        pi += __shfl_xor(pi, 4, 64); pj += __shfl_xor(pj, 4, 64);
        if (d == 0) {
            const int hd = o >> 3;
            eiL[n * NH + hd] = (pi + abv) * LOG2E;
            ejL[n * NH + hd] = pj * LOG2E;
        }
    }
}

// K2: 8 i-rows per block, 1024 threads = 128 j-lanes x 8 heads (16 waves).
// NO min-waves in launch_bounds: needs ~110 VGPR (acc[8][8]); a forced 64-cap
// spilled to scratch in R3 (WRITE_SIZE 31MB, 48.8us). ~110 VGPR -> 4 waves/SIMD.
__global__ __launch_bounds__(1024) void gat_main(
    const int* __restrict__ adj, const float* __restrict__ wh,
    const float* __restrict__ eiL, const float* __restrict__ ejL,
    float* __restrict__ out)
{
    __shared__ unsigned char s_bits[NN];     // 2 KB
    __shared__ float s_red[16][8][8][9];     // 36 KB: wave, head, i, d/den
    const int t  = threadIdx.x;
    const int i0 = blockIdx.x * 8;

    {   // stage + bit-pack: thread t owns columns 2t, 2t+1
        unsigned int b0 = 0, b1 = 0;
#pragma unroll
        for (int i = 0; i < 8; ++i) {
            const int2 v = *(const int2*)(adj + (size_t)(i0 + i) * NN + 2 * t);
            b0 |= (v.x != 0) << i;
            b1 |= (v.y != 0) << i;
        }
        s_bits[2 * t]     = (unsigned char)b0;
        s_bits[2 * t + 1] = (unsigned char)b1;
    }
    __syncthreads();

    const int hh = t & 7;
    const int jj = t >> 3;                   // 0..127
    float eih[8];
#pragma unroll
    for (int i = 0; i < 8; ++i) eih[i] = eiL[(i0 + i) * NH + hh];

    float den[8];
    float acc[8][8];
#pragma unroll
    for (int i = 0; i < 8; ++i) {
        den[i] = 0.f;
#pragma unroll
        for (int d2 = 0; d2 < 8; ++d2) acc[i][d2] = 0.f;
    }

    for (int it = 0; it < NN / 128; ++it) {
        const int j = (it << 7) | jj;
        const int bits = s_bits[j];
        const float ejv = ejL[j * NH + hh];
        const float4* wr = (const float4*)(wh + (size_t)j * ODIM + hh * DHD);
        const float4 w0 = wr[0];
        const float4 w1 = wr[1];
#pragma unroll
        for (int i = 0; i < 8; ++i) {
            float s = eih[i] + ejv;          // score * log2e
            s = fmaxf(s, 0.2f * s);          // LeakyReLU (commutes with +scale)
            // mask folded into exponent: exp2(s-192) flushes to exactly 0
            s += (bits & (1 << i)) ? 0.0f : -192.0f;
            const float w = exp2f(s);
            den[i] += w;
            acc[i][0] = fmaf(w, w0.x, acc[i][0]);
            acc[i][1] = fmaf(w, w0.y, acc[i][1]);
            acc[i][2] = fmaf(w, w0.z, acc[i][2]);
            acc[i][3] = fmaf(w, w0.w, acc[i][3]);
            acc[i][4] = fmaf(w, w1.x, acc[i][4]);
            acc[i][5] = fmaf(w, w1.y, acc[i][5]);
            acc[i][6] = fmaf(w, w1.z, acc[i][6]);
            acc[i][7] = fmaf(w, w1.w, acc[i][7]);
        }
    }

    // reduce over the 8 j-lane groups within each wave (lane bits 3..5)
#pragma unroll
    for (int m = 8; m <= 32; m <<= 1) {
#pragma unroll
        for (int i = 0; i < 8; ++i) {
            den[i] += __shfl_xor(den[i], m, 64);
#pragma unroll
            for (int d2 = 0; d2 < 8; ++d2)
                acc[i][d2] += __shfl_xor(acc[i][d2], m, 64);
        }
    }
    const int lane = t & 63;
    const int wv   = t >> 6;                 // 0..15
    if (lane < 8) {                          // lane == head
#pragma unroll
        for (int i = 0; i < 8; ++i) {
#pragma unroll
            for (int d2 = 0; d2 < 8; ++d2) s_red[wv][lane][i][d2] = acc[i][d2];
            s_red[wv][lane][i][8] = den[i];
        }
    }
    __syncthreads();

    if (t < 512) {                           // 8 i x 8 heads x 8 d
        const int i  = t >> 6;
        const int oh = (t >> 3) & 7;
        const int d2 = t & 7;
        float v = 0.f, dn = 0.f;
#pragma unroll
        for (int w2 = 0; w2 < 16; ++w2) {
            v  += s_red[w2][oh][i][d2];
            dn += s_red[w2][oh][i][8];
        }
        float r = v / dn;
        r = (r > 0.f) ? r : expm1f(r);       // ELU(alpha=1)
        out[(size_t)oh * (NN * DHD) + (size_t)(i0 + i) * DHD + d2] = r;
    }
}

extern "C" void kernel_launch(void* const* d_in, const int* in_sizes, int n_in,
                              void* d_out, int out_size, void* d_ws, size_t ws_size,
                              hipStream_t stream) {
    const float* h   = (const float*)d_in[0];
    const int*   adj = (const int*)d_in[1];
    const float* Ww  = (const float*)d_in[2];
    const float* Wb  = (const float*)d_in[3];
    const float* aw  = (const float*)d_in[4];
    const float* ab  = (const float*)d_in[5];
    float* out = (float*)d_out;

    float* wh  = (float*)d_ws;                // 2048*64 f32
    float* eiL = wh + (size_t)NN * ODIM;      // 2048*8
    float* ejL = eiL + (size_t)NN * NH;       // 2048*8

    gat_pre<<<NN / 8, 256, 0, stream>>>(h, Ww, Wb, aw, ab, wh, eiL, ejL);
    gat_main<<<NN / 8, 1024, 0, stream>>>(adj, wh, eiL, ejL, out);
}